// Round 4
// baseline (185.783 us; speedup 1.0000x reference)
//
#include <hip/hip_runtime.h>
#include <hip/hip_bf16.h>

#define B_ 64
#define C_ 512
#define HW_ 1024
#define R_ 32
#define NCHUNK 4
#define CPB 128  // C_ / NCHUNK

// ---------------------------------------------------------------------------
// A0: transpose w_eig (R,C) -> wt (C,R) so the projection loop reads 32
// contiguous wave-uniform floats per channel (s_load / dwordx4 friendly).
// ---------------------------------------------------------------------------
__global__ void k_transpose_w(const float* __restrict__ w_eig,
                              float* __restrict__ wt) {
    int idx = blockIdx.x * 1024 + threadIdx.x;   // grid 16 x 1024 = 16384
    int r = idx >> 9;
    int c = idx & 511;
    wt[c * R_ + r] = w_eig[idx];                 // w_eig[r*512 + c]
}

// ---------------------------------------------------------------------------
// A: one pass over x. Block = (b, c-chunk), 1024 threads = one per pixel n.
// Per channel c: feat[r] += w_eig[r,c]*x, sp += w_sp[c]*x, pooled[c] via
// wave butterfly. Writes bf16 feat partials in [.. n][r] layout (16B/lane).
// ---------------------------------------------------------------------------
__global__ __launch_bounds__(1024) void k_proj(
    const float* __restrict__ x, const float* __restrict__ wt,
    const float* __restrict__ w_sp,
    __hip_bfloat16* __restrict__ featp, float* __restrict__ spp,
    float* __restrict__ pooled)
{
    const int n    = threadIdx.x;
    const int blk  = blockIdx.x;
    const int b    = blk >> 2;
    const int ch   = blk & 3;
    const int c0   = ch * CPB;
    const int wave = n >> 6;
    const int lane = n & 63;

    __shared__ float pool_part[CPB][17];

    float acc[R_];
#pragma unroll
    for (int r = 0; r < R_; ++r) acc[r] = 0.f;
    float sp = 0.f;

    const float* xb = x + ((size_t)(b * C_ + c0)) * HW_ + n;

    for (int j = 0; j < CPB; ++j) {
        float xv = xb[(size_t)j * HW_];

        const float4* wc = (const float4*)(wt + (size_t)(c0 + j) * R_);
        union { float4 v4[8]; float f[R_]; } wu;
#pragma unroll
        for (int k = 0; k < 8; ++k) wu.v4[k] = wc[k];
#pragma unroll
        for (int r = 0; r < R_; ++r) acc[r] = fmaf(wu.f[r], xv, acc[r]);

        sp = fmaf(w_sp[c0 + j], xv, sp);

        // per-channel pooled partial: butterfly sum over the wave's 64 pixels
        float s = xv;
#pragma unroll
        for (int m = 32; m > 0; m >>= 1) s += __shfl_xor(s, m, 64);
        if (lane == 0) pool_part[j][wave] = s;
    }
    __syncthreads();

    if (n < CPB) {
        float s = 0.f;
#pragma unroll
        for (int w = 0; w < 16; ++w) s += pool_part[n][w];
        pooled[b * C_ + c0 + n] = s;   // SUM over n (mean applied later)
    }

    spp[((size_t)(ch * B_ + b)) * HW_ + n] = sp;

    // bf16 feat partial, layout [(ch*B+b)*HW + n][r] -> 64B per thread
    union { __hip_bfloat16 h[R_]; uint4 q[4]; } u;
#pragma unroll
    for (int r = 0; r < R_; ++r) u.h[r] = __float2bfloat16(acc[r]);
    uint4* dst = (uint4*)(featp + ((size_t)((ch * B_ + b) * HW_ + n)) * R_);
#pragma unroll
    for (int k = 0; k < 4; ++k) dst[k] = u.q[k];
}

// ---------------------------------------------------------------------------
// B: per-batch block (64 blocks, 1024 threads = one per pixel).
// mean[r] & fc1 from pooled; channel attention; power iteration with the
// column F_c[:,n] held in registers (cov@v = F(F^T v)/1023 + 1e-5 v);
// att -> min/max -> sigmoid; att_all = eigen_att * spatial_att.
// ---------------------------------------------------------------------------
__global__ __launch_bounds__(1024) void k_eigen(
    const __hip_bfloat16* __restrict__ featp, const float* __restrict__ spp,
    const float* __restrict__ pooled,
    const float* __restrict__ w_eig, const float* __restrict__ w_fc1,
    const float* __restrict__ b_fc1, const float* __restrict__ w_fc2,
    const float* __restrict__ b_fc2, const float* __restrict__ b_sp,
    const float* __restrict__ v0,
    float* __restrict__ ca_out, float* __restrict__ att_out)
{
    const int b    = blockIdx.x;
    const int t    = threadIdx.x;
    const int lane = t & 63;
    const int wave = t >> 6;

    __shared__ float meanv[R_], t1[R_], vv[R_];
    __shared__ float part[R_][17];
    __shared__ float redmn[16], redmx[16], scal[2];

    // ---- mean[r] = (w_eig @ pooled_mean)[r]; t1[r] = relu(fc1 @ pooled_mean + b)
    if (t < 512) {
        const int r = t >> 4, k = t & 15;
        float pm = 0.f, pf = 0.f;
        for (int c = k; c < C_; c += 16) {
            float p = pooled[b * C_ + c] * (1.f / 1024.f);
            pm = fmaf(w_eig[r * C_ + c], p, pm);
            pf = fmaf(w_fc1[r * C_ + c], p, pf);
        }
#pragma unroll
        for (int m = 8; m > 0; m >>= 1) {
            pm += __shfl_xor(pm, m, 64);
            pf += __shfl_xor(pf, m, 64);
        }
        if (k == 0) { meanv[r] = pm; t1[r] = fmaxf(pf + b_fc1[r], 0.f); }
    }
    __syncthreads();

    // ---- channel attention ca[c] = sigmoid(w_fc2[c,:] @ t1 + b_fc2[c])
    if (t < C_) {
        float s = b_fc2[t];
        const float4* w4 = (const float4*)(w_fc2 + (size_t)t * R_);
#pragma unroll
        for (int k = 0; k < 8; ++k) {
            float4 w = w4[k];
            s = fmaf(w.x, t1[4 * k + 0], s);
            s = fmaf(w.y, t1[4 * k + 1], s);
            s = fmaf(w.z, t1[4 * k + 2], s);
            s = fmaf(w.w, t1[4 * k + 3], s);
        }
        ca_out[b * C_ + t] = 1.f / (1.f + expf(-s));
    }

    // ---- build centered column F_c[:, t] in registers (b_eig cancels)
    float col[R_];
#pragma unroll
    for (int r = 0; r < R_; ++r) col[r] = -meanv[r];
    for (int ch = 0; ch < NCHUNK; ++ch) {
        union { __hip_bfloat16 h[R_]; uint4 q[4]; } u;
        const uint4* src =
            (const uint4*)(featp + ((size_t)((ch * B_ + b) * HW_ + t)) * R_);
#pragma unroll
        for (int k = 0; k < 4; ++k) u.q[k] = src[k];
#pragma unroll
        for (int r = 0; r < R_; ++r) col[r] += __bfloat162float(u.h[r]);
    }

    // ---- v = v0 / ||v0||
    if (t < 64) {
        float vl = (t < R_) ? v0[b * R_ + t] : 0.f;
        float sq = vl * vl;
#pragma unroll
        for (int m = 32; m > 0; m >>= 1) sq += __shfl_xor(sq, m, 64);
        if (t < R_) vv[t] = vl / sqrtf(sq);
    }
    __syncthreads();

    // ---- 5 power iterations: v <- normalize(F (F^T v)/1023 + 1e-5 v)
    for (int it = 0; it < 5; ++it) {
        float uacc = 0.f;
#pragma unroll
        for (int r = 0; r < R_; ++r) uacc = fmaf(col[r], vv[r], uacc);
        uacc *= (1.f / 1023.f);

#pragma unroll
        for (int r = 0; r < R_; ++r) {
            float s = col[r] * uacc;
#pragma unroll
            for (int m = 32; m > 0; m >>= 1) s += __shfl_xor(s, m, 64);
            if (lane == 0) part[r][wave] = s;
        }
        __syncthreads();

        if (t < 64) {
            float w = 0.f;
            if (t < R_) {
                w = 1e-5f * vv[t];
#pragma unroll
                for (int wv = 0; wv < 16; ++wv) w += part[t][wv];
            }
            float sq = w * w;
#pragma unroll
            for (int m = 32; m > 0; m >>= 1) sq += __shfl_xor(sq, m, 64);
            if (t < R_) vv[t] = w / (sqrtf(sq) + 1e-10f);
        }
        __syncthreads();
    }

    // ---- att, min/max, eigen_att, spatial_att
    float a = 0.f;
#pragma unroll
    for (int r = 0; r < R_; ++r) a = fmaf(col[r], vv[r], a);

    float mn = a, mx = a;
#pragma unroll
    for (int m = 32; m > 0; m >>= 1) {
        mn = fminf(mn, __shfl_xor(mn, m, 64));
        mx = fmaxf(mx, __shfl_xor(mx, m, 64));
    }
    if (lane == 0) { redmn[wave] = mn; redmx[wave] = mx; }
    __syncthreads();
    if (t == 0) {
        float m1 = redmn[0], m2 = redmx[0];
        for (int w = 1; w < 16; ++w) {
            m1 = fminf(m1, redmn[w]);
            m2 = fmaxf(m2, redmx[w]);
        }
        scal[0] = m1; scal[1] = m2;
    }
    __syncthreads();

    const float amin  = scal[0];
    const float denom = (scal[1] - scal[0]) + 1e-10f;
    float eig = 1.f / (1.f + expf(-((a - amin) / denom)));

    float ssum = b_sp[0];
#pragma unroll
    for (int ch = 0; ch < NCHUNK; ++ch)
        ssum += spp[((size_t)(ch * B_ + b)) * HW_ + t];
    float spsig = 1.f / (1.f + expf(-ssum));

    att_out[b * HW_ + t] = eig * spsig;
}

// ---------------------------------------------------------------------------
// C: out = x * (1 + ca[b,c] * att_all[b,n]), float4 streaming.
// Block = one (b,c) row of 1024 floats; 256 threads x float4.
// ---------------------------------------------------------------------------
__global__ __launch_bounds__(256) void k_final(
    const float* __restrict__ x, const float* __restrict__ ca,
    const float* __restrict__ att, float* __restrict__ out)
{
    const int t   = threadIdx.x;
    const int blk = blockIdx.x;          // b*C_ + c
    const int b   = blk >> 9;
    const float cav  = ca[blk];
    const size_t base = (size_t)blk * HW_;

    float4 xv = ((const float4*)(x + base))[t];
    float4 av = ((const float4*)(att + (size_t)b * HW_))[t];
    float4 o;
    o.x = fmaf(xv.x * cav, av.x, xv.x);
    o.y = fmaf(xv.y * cav, av.y, xv.y);
    o.z = fmaf(xv.z * cav, av.z, xv.z);
    o.w = fmaf(xv.w * cav, av.w, xv.w);
    ((float4*)(out + base))[t] = o;
}

// ---------------------------------------------------------------------------
extern "C" void kernel_launch(void* const* d_in, const int* in_sizes, int n_in,
                              void* d_out, int out_size, void* d_ws, size_t ws_size,
                              hipStream_t stream) {
    const float* x     = (const float*)d_in[0];
    const float* w_fc1 = (const float*)d_in[1];
    const float* b_fc1 = (const float*)d_in[2];
    const float* w_fc2 = (const float*)d_in[3];
    const float* b_fc2 = (const float*)d_in[4];
    const float* w_eig = (const float*)d_in[5];
    // d_in[6] = b_eig: cancels under mean-centering; unused.
    const float* w_sp  = (const float*)d_in[7];
    const float* b_sp  = (const float*)d_in[8];
    const float* v0    = (const float*)d_in[9];
    float* out = (float*)d_out;

    // workspace layout (bytes); total 18,415,616
    char* ws = (char*)d_ws;
    __hip_bfloat16* featp = (__hip_bfloat16*)ws;             // 16,777,216: 4*64*1024*32 bf16
    float* spp    = (float*)(ws + 16777216);                 //  1,048,576: 4*64*1024 f32
    float* pooled = (float*)(ws + 17825792);                 //    131,072: 64*512 f32 (sums)
    float* ca     = (float*)(ws + 17956864);                 //    131,072: 64*512 f32
    float* att    = (float*)(ws + 18087936);                 //    262,144: 64*1024 f32
    float* wt     = (float*)(ws + 18350080);                 //     65,536: 512*32 f32

    k_transpose_w<<<16, 1024, 0, stream>>>(w_eig, wt);
    k_proj<<<B_ * NCHUNK, 1024, 0, stream>>>(x, wt, w_sp, featp, spp, pooled);
    k_eigen<<<B_, 1024, 0, stream>>>(featp, spp, pooled, w_eig, w_fc1, b_fc1,
                                     w_fc2, b_fc2, b_sp, v0, ca, att);
    k_final<<<B_ * C_, 256, 0, stream>>>(x, ca, att, out);
}

// Round 5
// 165.035 us; speedup vs baseline: 1.1257x; 1.1257x over previous
//
#include <hip/hip_runtime.h>
#include <hip/hip_bf16.h>

#define B_ 64
#define C_ 512
#define HW_ 1024
#define R_ 32
#define NCHUNK 4
#define CPB 128  // channels per chunk

__device__ __forceinline__ float4 fma4(float s, float4 v, float4 a) {
    a.x = fmaf(s, v.x, a.x);
    a.y = fmaf(s, v.y, a.y);
    a.z = fmaf(s, v.z, a.z);
    a.w = fmaf(s, v.w, a.w);
    return a;
}

// ---------------------------------------------------------------------------
// A0: transpose w_eig (R,C) -> wt (C,R): per-channel rows of 32 contiguous.
// ---------------------------------------------------------------------------
__global__ void k_transpose_w(const float* __restrict__ w_eig,
                              float* __restrict__ wt) {
    int idx = blockIdx.x * 1024 + threadIdx.x;   // grid 16 x 1024 = 16384
    int r = idx >> 9;
    int c = idx & 511;
    wt[c * R_ + r] = w_eig[idx];                 // w_eig[r*512 + c]
}

// ---------------------------------------------------------------------------
// A: one pass over x. Block = (b, c-chunk); 256 threads, 4 pixels/thread.
// Weights staged in LDS (broadcast reads); pooled via cheap per-iter partial
// (float4 collapse + 2 shuffles + 1 LDS store) reduced once at the end.
// ---------------------------------------------------------------------------
__global__ __launch_bounds__(256, 1) void k_proj(
    const float* __restrict__ x, const float* __restrict__ wt,
    const float* __restrict__ w_sp,
    __hip_bfloat16* __restrict__ featp, float* __restrict__ spp,
    float* __restrict__ pooled)
{
    const int t   = threadIdx.x;       // 0..255, pixels 4t..4t+3
    const int blk = blockIdx.x;        // b*4 + ch
    const int b   = blk >> 2;
    const int ch  = blk & 3;
    const int c0  = ch * CPB;

    __shared__ float wlds[CPB * R_];   // 16 KB: weight rows, 32 floats each
    __shared__ float wsp_l[CPB];       // 512 B
    __shared__ float plds[CPB][65];    // 33.3 KB: pooled partials (padded)
    __shared__ float red[CPB][2];

    for (int i = t; i < CPB * R_; i += 256) wlds[i] = wt[c0 * R_ + i];
    for (int i = t; i < CPB; i += 256)      wsp_l[i] = w_sp[c0 + i];
    __syncthreads();

    float4 acc[R_];
#pragma unroll
    for (int r = 0; r < R_; ++r) acc[r] = make_float4(0.f, 0.f, 0.f, 0.f);
    float4 sp = make_float4(0.f, 0.f, 0.f, 0.f);

    const float4* xb = (const float4*)(x + ((size_t)(b * C_ + c0)) * HW_) + t;

    float4 xv = xb[0];
    for (int j = 0; j < CPB; ++j) {
        // prefetch next channel's pixels (wraps harmlessly on last iter)
        float4 xn = xb[((j + 1) & (CPB - 1)) * (HW_ / 4)];

        const float4* wr = (const float4*)(wlds + j * R_);  // uniform addr
#pragma unroll
        for (int k = 0; k < 8; ++k) {
            float4 w = wr[k];
            acc[4 * k + 0] = fma4(w.x, xv, acc[4 * k + 0]);
            acc[4 * k + 1] = fma4(w.y, xv, acc[4 * k + 1]);
            acc[4 * k + 2] = fma4(w.z, xv, acc[4 * k + 2]);
            acc[4 * k + 3] = fma4(w.w, xv, acc[4 * k + 3]);
        }

        sp = fma4(wsp_l[j], xv, sp);

        // pooled partial: collapse own 4 px, fold 4-lane group, 1 LDS store
        float s = (xv.x + xv.y) + (xv.z + xv.w);
        s += __shfl_xor(s, 1, 64);
        s += __shfl_xor(s, 2, 64);
        if ((t & 3) == 0) plds[j][t >> 2] = s;   // 64 partials per channel

        xv = xn;
    }
    __syncthreads();

    // pooled final reduce: thread t -> channel t>>1, half t&1
    {
        const int j = t >> 1, h = t & 1;
        float s = 0.f;
#pragma unroll
        for (int i = 0; i < 32; ++i) s += plds[j][h * 32 + i];
        red[j][h] = s;
    }
    __syncthreads();
    if (t < CPB) pooled[b * C_ + c0 + t] = red[t][0] + red[t][1];  // SUM over n

    ((float4*)(spp + ((size_t)(ch * B_ + b)) * HW_))[t] = sp;

    // featp bf16, layout [(ch*B+b)*HW + n][r]; this thread owns n = 4t..4t+3
    __hip_bfloat16* fb = featp + ((size_t)((ch * B_ + b) * HW_ + 4 * t)) * R_;
    union { __hip_bfloat16 h[R_]; uint4 q[4]; } u;

#pragma unroll
    for (int r = 0; r < R_; ++r) u.h[r] = __float2bfloat16(acc[r].x);
#pragma unroll
    for (int k = 0; k < 4; ++k) ((uint4*)fb)[k] = u.q[k];
#pragma unroll
    for (int r = 0; r < R_; ++r) u.h[r] = __float2bfloat16(acc[r].y);
#pragma unroll
    for (int k = 0; k < 4; ++k) ((uint4*)(fb + R_))[k] = u.q[k];
#pragma unroll
    for (int r = 0; r < R_; ++r) u.h[r] = __float2bfloat16(acc[r].z);
#pragma unroll
    for (int k = 0; k < 4; ++k) ((uint4*)(fb + 2 * R_))[k] = u.q[k];
#pragma unroll
    for (int r = 0; r < R_; ++r) u.h[r] = __float2bfloat16(acc[r].w);
#pragma unroll
    for (int k = 0; k < 4; ++k) ((uint4*)(fb + 3 * R_))[k] = u.q[k];
}

// ---------------------------------------------------------------------------
// B: per-batch block (64 blocks, 1024 threads = one per pixel).
// mean[r] & fc1 from pooled; channel attention; power iteration with the
// column F_c[:,n] held in registers (cov@v = F(F^T v)/1023 + 1e-5 v);
// att -> min/max -> sigmoid; att_all = eigen_att * spatial_att.
// ---------------------------------------------------------------------------
__global__ __launch_bounds__(1024) void k_eigen(
    const __hip_bfloat16* __restrict__ featp, const float* __restrict__ spp,
    const float* __restrict__ pooled,
    const float* __restrict__ w_eig, const float* __restrict__ w_fc1,
    const float* __restrict__ b_fc1, const float* __restrict__ w_fc2,
    const float* __restrict__ b_fc2, const float* __restrict__ b_sp,
    const float* __restrict__ v0,
    float* __restrict__ ca_out, float* __restrict__ att_out)
{
    const int b    = blockIdx.x;
    const int t    = threadIdx.x;
    const int lane = t & 63;
    const int wave = t >> 6;

    __shared__ float meanv[R_], t1[R_], vv[R_];
    __shared__ float part[R_][17];
    __shared__ float redmn[16], redmx[16], scal[2];

    // ---- mean[r] = (w_eig @ pooled_mean)[r]; t1[r] = relu(fc1 @ pooled_mean + b)
    if (t < 512) {
        const int r = t >> 4, k = t & 15;
        float pm = 0.f, pf = 0.f;
        for (int c = k; c < C_; c += 16) {
            float p = pooled[b * C_ + c] * (1.f / 1024.f);
            pm = fmaf(w_eig[r * C_ + c], p, pm);
            pf = fmaf(w_fc1[r * C_ + c], p, pf);
        }
#pragma unroll
        for (int m = 8; m > 0; m >>= 1) {
            pm += __shfl_xor(pm, m, 64);
            pf += __shfl_xor(pf, m, 64);
        }
        if (k == 0) { meanv[r] = pm; t1[r] = fmaxf(pf + b_fc1[r], 0.f); }
    }
    __syncthreads();

    // ---- channel attention ca[c] = sigmoid(w_fc2[c,:] @ t1 + b_fc2[c])
    if (t < C_) {
        float s = b_fc2[t];
        const float4* w4 = (const float4*)(w_fc2 + (size_t)t * R_);
#pragma unroll
        for (int k = 0; k < 8; ++k) {
            float4 w = w4[k];
            s = fmaf(w.x, t1[4 * k + 0], s);
            s = fmaf(w.y, t1[4 * k + 1], s);
            s = fmaf(w.z, t1[4 * k + 2], s);
            s = fmaf(w.w, t1[4 * k + 3], s);
        }
        ca_out[b * C_ + t] = 1.f / (1.f + expf(-s));
    }

    // ---- build centered column F_c[:, t] in registers (b_eig cancels)
    float col[R_];
#pragma unroll
    for (int r = 0; r < R_; ++r) col[r] = -meanv[r];
    for (int ch = 0; ch < NCHUNK; ++ch) {
        union { __hip_bfloat16 h[R_]; uint4 q[4]; } u;
        const uint4* src =
            (const uint4*)(featp + ((size_t)((ch * B_ + b) * HW_ + t)) * R_);
#pragma unroll
        for (int k = 0; k < 4; ++k) u.q[k] = src[k];
#pragma unroll
        for (int r = 0; r < R_; ++r) col[r] += __bfloat162float(u.h[r]);
    }

    // ---- v = v0 / ||v0||
    if (t < 64) {
        float vl = (t < R_) ? v0[b * R_ + t] : 0.f;
        float sq = vl * vl;
#pragma unroll
        for (int m = 32; m > 0; m >>= 1) sq += __shfl_xor(sq, m, 64);
        if (t < R_) vv[t] = vl / sqrtf(sq);
    }
    __syncthreads();

    // ---- 5 power iterations: v <- normalize(F (F^T v)/1023 + 1e-5 v)
    for (int it = 0; it < 5; ++it) {
        float uacc = 0.f;
#pragma unroll
        for (int r = 0; r < R_; ++r) uacc = fmaf(col[r], vv[r], uacc);
        uacc *= (1.f / 1023.f);

#pragma unroll
        for (int r = 0; r < R_; ++r) {
            float s = col[r] * uacc;
#pragma unroll
            for (int m = 32; m > 0; m >>= 1) s += __shfl_xor(s, m, 64);
            if (lane == 0) part[r][wave] = s;
        }
        __syncthreads();

        if (t < 64) {
            float w = 0.f;
            if (t < R_) {
                w = 1e-5f * vv[t];
#pragma unroll
                for (int wv = 0; wv < 16; ++wv) w += part[t][wv];
            }
            float sq = w * w;
#pragma unroll
            for (int m = 32; m > 0; m >>= 1) sq += __shfl_xor(sq, m, 64);
            if (t < R_) vv[t] = w / (sqrtf(sq) + 1e-10f);
        }
        __syncthreads();
    }

    // ---- att, min/max, eigen_att, spatial_att
    float a = 0.f;
#pragma unroll
    for (int r = 0; r < R_; ++r) a = fmaf(col[r], vv[r], a);

    float mn = a, mx = a;
#pragma unroll
    for (int m = 32; m > 0; m >>= 1) {
        mn = fminf(mn, __shfl_xor(mn, m, 64));
        mx = fmaxf(mx, __shfl_xor(mx, m, 64));
    }
    if (lane == 0) { redmn[wave] = mn; redmx[wave] = mx; }
    __syncthreads();
    if (t == 0) {
        float m1 = redmn[0], m2 = redmx[0];
        for (int w = 1; w < 16; ++w) {
            m1 = fminf(m1, redmn[w]);
            m2 = fmaxf(m2, redmx[w]);
        }
        scal[0] = m1; scal[1] = m2;
    }
    __syncthreads();

    const float amin  = scal[0];
    const float denom = (scal[1] - scal[0]) + 1e-10f;
    float eig = 1.f / (1.f + expf(-((a - amin) / denom)));

    float ssum = b_sp[0];
#pragma unroll
    for (int ch = 0; ch < NCHUNK; ++ch)
        ssum += spp[((size_t)(ch * B_ + b)) * HW_ + t];
    float spsig = 1.f / (1.f + expf(-ssum));

    att_out[b * HW_ + t] = eig * spsig;
}

// ---------------------------------------------------------------------------
// C: out = x * (1 + ca[b,c] * att_all[b,n]), float4 streaming.
// ---------------------------------------------------------------------------
__global__ __launch_bounds__(256) void k_final(
    const float* __restrict__ x, const float* __restrict__ ca,
    const float* __restrict__ att, float* __restrict__ out)
{
    const int t   = threadIdx.x;
    const int blk = blockIdx.x;          // b*C_ + c
    const int b   = blk >> 9;
    const float cav  = ca[blk];
    const size_t base = (size_t)blk * HW_;

    float4 xv = ((const float4*)(x + base))[t];
    float4 av = ((const float4*)(att + (size_t)b * HW_))[t];
    float4 o;
    o.x = fmaf(xv.x * cav, av.x, xv.x);
    o.y = fmaf(xv.y * cav, av.y, xv.y);
    o.z = fmaf(xv.z * cav, av.z, xv.z);
    o.w = fmaf(xv.w * cav, av.w, xv.w);
    ((float4*)(out + base))[t] = o;
}

// ---------------------------------------------------------------------------
extern "C" void kernel_launch(void* const* d_in, const int* in_sizes, int n_in,
                              void* d_out, int out_size, void* d_ws, size_t ws_size,
                              hipStream_t stream) {
    const float* x     = (const float*)d_in[0];
    const float* w_fc1 = (const float*)d_in[1];
    const float* b_fc1 = (const float*)d_in[2];
    const float* w_fc2 = (const float*)d_in[3];
    const float* b_fc2 = (const float*)d_in[4];
    const float* w_eig = (const float*)d_in[5];
    // d_in[6] = b_eig: cancels under mean-centering; unused.
    const float* w_sp  = (const float*)d_in[7];
    const float* b_sp  = (const float*)d_in[8];
    const float* v0    = (const float*)d_in[9];
    float* out = (float*)d_out;

    // workspace layout (bytes); total 18,415,616 (identical to passing round)
    char* ws = (char*)d_ws;
    __hip_bfloat16* featp = (__hip_bfloat16*)ws;             // 16,777,216: 4*64*1024*32 bf16
    float* spp    = (float*)(ws + 16777216);                 //  1,048,576: 4*64*1024 f32
    float* pooled = (float*)(ws + 17825792);                 //    131,072: 64*512 f32 (sums)
    float* ca     = (float*)(ws + 17956864);                 //    131,072: 64*512 f32
    float* att    = (float*)(ws + 18087936);                 //    262,144: 64*1024 f32
    float* wt     = (float*)(ws + 18350080);                 //     65,536: 512*32 f32

    k_transpose_w<<<16, 1024, 0, stream>>>(w_eig, wt);
    k_proj<<<B_ * NCHUNK, 256, 0, stream>>>(x, wt, w_sp, featp, spp, pooled);
    k_eigen<<<B_, 1024, 0, stream>>>(featp, spp, pooled, w_eig, w_fc1, b_fc1,
                                     w_fc2, b_fc2, b_sp, v0, ca, att);
    k_final<<<B_ * C_, 256, 0, stream>>>(x, ca, att, out);
}